// Round 3
// baseline (91.592 us; speedup 1.0000x reference)
//
#include <hip/hip_runtime.h>

// Problem constants (B=1, C=1, H=W=96)
#define NPTS  9216
#define WIDTH 96
#define TILE  256          // i-tile = j-tile = 256 points
#define NT    36           // 9216/256 tiles
#define IPT   2            // i-points per thread (block = 128 threads)

// Prescale features by sqrt(log2(e)) so exp(-0.5 d2) == exp2(hs_i + hs_j + dot)
#define KSCALE 1.2011224087864498f   // sqrt(1.4426950408889634)

typedef _Float16 half2v __attribute__((ext_vector_type(2)));
union H2F { half2v h; float f; };

// Kernel 1: build packed per-point records.
//  arrF[p] = { h2(x,y), h2(r,g), h2(b,0), hs = -0.5|f|^2*log2e }   (16 B)
//  arrS[p] = s                                                      (4 B)
// |f|^2 uses the fp16-ROUNDED features so the diagonal w_ii == 1 exactly.
__global__ __launch_bounds__(256)
void crf_feat_kernel(const float* __restrict__ s,
                     const float* __restrict__ img,
                     float4* __restrict__ arrF,
                     float* __restrict__ arrS,
                     float* __restrict__ out) {
    int p = blockIdx.x * 256 + threadIdx.x;
    if (p == 0) out[0] = 0.0f;            // harness re-poisons d_out every launch
    if (p >= NPTS) return;
    int y = p / WIDTH;
    int x = p - y * WIDTH;
    float sv = s[p];
    float xs = (float)x * (KSCALE / 15.0f);
    float ys = (float)y * (KSCALE / 15.0f);
    float rs = img[p]          * (8.0f * KSCALE);
    float gs = img[NPTS + p]   * (8.0f * KSCALE);
    float bs = img[2*NPTS + p] * (8.0f * KSCALE);
    _Float16 xh = (_Float16)xs, yh = (_Float16)ys;
    _Float16 rh = (_Float16)rs, gh = (_Float16)gs, bh = (_Float16)bs;
    float xr = (float)xh, yr = (float)yh, rr = (float)rh, gr = (float)gh, br = (float)bh;
    float hs = -0.5f * (xr*xr + yr*yr + rr*rr + gr*gr + br*br);

    H2F xy; xy.h = half2v{xh, yh};
    H2F rg; rg.h = half2v{rh, gh};
    H2F b0; b0.h = half2v{bh, (_Float16)0.0f};

    float4 r;
    r.x = xy.f; r.y = rg.f; r.z = b0.f; r.w = hs;
    arrF[p] = r;
    arrS[p] = sv;
}

// Kernel 2: grid 36x36 tile pairs, upper triangle only (jb >= ib).
// Symmetric form: sum over tile pair of w_ij * g_ij, g = s_i + s_j - 2 s_i s_j,
// with factor 0.5 on diagonal tiles (which also yields the exact i==j term).
// j-records are wave-uniform -> s_load into SGPRs; no LDS staging at all.
__global__ __launch_bounds__(128)
void crf_pair_kernel(const float4* __restrict__ arrF,
                     const float* __restrict__ arrS,
                     float* __restrict__ out) {
    const int ib = blockIdx.x;
    const int jb = blockIdx.y;
    if (jb < ib) return;                 // lower triangle: whole block exits

    __shared__ float wavesum[2];
    const int tid   = threadIdx.x;       // 128 threads
    const int ibase = ib * TILE;
    const int jbase = jb * TILE;

    // My IPT=2 i-points (vector loads, L2-resident).
    half2v xyi[IPT], rgi[IPT], b0i[IPT];
    float  hsi[IPT], svi[IPT];
    #pragma unroll
    for (int k = 0; k < IPT; ++k) {
        int i = ibase + k * 128 + tid;
        float4 r = arrF[i];
        H2F a; a.f = r.x; xyi[k] = a.h;
        H2F b; b.f = r.y; rgi[k] = b.h;
        H2F c; c.f = r.z; b0i[k] = c.h;
        hsi[k] = r.w;
        svi[k] = arrS[i];
    }

    float acc[IPT] = {0.0f, 0.0f};

    #pragma unroll 4
    for (int j = 0; j < TILE; ++j) {
        const float4 fj = arrF[jbase + j];   // uniform -> scalar load
        const float  sj = arrS[jbase + j];   // uniform -> scalar load
        const float  cj = 1.0f - 2.0f * sj;  // scalar ALU
        H2F a; a.f = fj.x;
        H2F b; b.f = fj.y;
        H2F c; c.f = fj.z;
        const half2v xyj = a.h, rgj = b.h, b0j = c.h;
        #pragma unroll
        for (int k = 0; k < IPT; ++k) {
            float e = hsi[k] + fj.w;
            e = __builtin_amdgcn_fdot2(xyi[k], xyj, e, false);
            e = __builtin_amdgcn_fdot2(rgi[k], rgj, e, false);
            e = __builtin_amdgcn_fdot2(b0i[k], b0j, e, false);
            float w = __builtin_amdgcn_exp2f(e);
            float g = fmaf(svi[k], cj, sj);      // s_i + s_j - 2 s_i s_j
            acc[k] = fmaf(w, g, acc[k]);
        }
    }

    float t = acc[0] + acc[1];
    const float factor = (ib == jb) ? 0.5f : 1.0f;
    t *= factor * (1.0f / (float)NPTS);

    #pragma unroll
    for (int off = 32; off > 0; off >>= 1)
        t += __shfl_down(t, off, 64);
    if ((tid & 63) == 0) wavesum[tid >> 6] = t;
    __syncthreads();
    if (tid == 0) atomicAdd(out, wavesum[0] + wavesum[1]);
}

extern "C" void kernel_launch(void* const* d_in, const int* in_sizes, int n_in,
                              void* d_out, int out_size, void* d_ws, size_t ws_size,
                              hipStream_t stream) {
    const float* s   = (const float*)d_in[0];   // [1,1,96,96] probs
    const float* img = (const float*)d_in[1];   // [1,3,96,96] rgb
    float* out = (float*)d_out;

    float4* arrF = (float4*)d_ws;               // 9216 * 16 B
    float*  arrS = (float*)(arrF + NPTS);       // 9216 * 4 B

    crf_feat_kernel<<<NPTS/256, 256, 0, stream>>>(s, img, arrF, arrS, out);
    dim3 grid(NT, NT);
    crf_pair_kernel<<<grid, 128, 0, stream>>>(arrF, arrS, out);
}

// Round 4
// 71.007 us; speedup vs baseline: 1.2899x; 1.2899x over previous
//
#include <hip/hip_runtime.h>

// Problem constants (B=1, C=1, H=W=96)
#define NPTS   9216
#define WIDTH  96
#define CHUNK  1024        // i/j chunk (256 threads x IPT=4)
#define NCHUNK 9           // 9216/1024
#define NPAIR  45          // NCHUNK*(NCHUNK+1)/2 unordered chunk pairs
#define JSUB   64          // j sub-tile staged in LDS
#define NJSUB  16          // 1024/64
#define IPT    4

// Prescale features by sqrt(log2(e)) so exp(-0.5 d2) == exp2(hs_i + hs_j + dot)
#define KSCALE 1.2011224087864498f

typedef _Float16 half2v __attribute__((ext_vector_type(2)));
union H2F { half2v h; float f; };

// Kernel 1: packed per-point records + zero the scalar output.
//  arrF[p] = { h2(x,y), h2(r,g), h2(b, s_fp16), hs = -0.5|f|^2*log2e }  (16 B)
//  arrS[p] = s (f32)                                                    (4 B)
// |f|^2 uses the fp16-ROUNDED features (b-lane only; s-lane excluded) so the
// diagonal w_ii == 1 to ~1 ulp.
__global__ __launch_bounds__(256)
void crf_feat_kernel(const float* __restrict__ s,
                     const float* __restrict__ img,
                     float4* __restrict__ arrF,
                     float* __restrict__ arrS,
                     float* __restrict__ out) {
    int p = blockIdx.x * 256 + threadIdx.x;
    if (p == 0) out[0] = 0.0f;            // harness re-poisons d_out every launch
    if (p >= NPTS) return;
    int y = p / WIDTH;
    int x = p - y * WIDTH;
    float sv = s[p];
    float xs = (float)x * (KSCALE / 15.0f);
    float ys = (float)y * (KSCALE / 15.0f);
    float rs = img[p]          * (8.0f * KSCALE);
    float gs = img[NPTS + p]   * (8.0f * KSCALE);
    float bs = img[2*NPTS + p] * (8.0f * KSCALE);
    _Float16 xh = (_Float16)xs, yh = (_Float16)ys;
    _Float16 rh = (_Float16)rs, gh = (_Float16)gs, bh = (_Float16)bs;
    float xr = (float)xh, yr = (float)yh, rr = (float)rh, gr = (float)gh, br = (float)bh;
    float hs = -0.5f * (xr*xr + yr*yr + rr*rr + gr*gr + br*br);

    H2F xy; xy.h = half2v{xh, yh};
    H2F rg; rg.h = half2v{rh, gh};
    H2F b0; b0.h = half2v{bh, (_Float16)sv};   // s_j rides the spare fp16 lane

    float4 r;
    r.x = xy.f; r.y = rg.f; r.z = b0.f; r.w = hs;
    arrF[p] = r;
    arrS[p] = sv;
}

// Kernel 2: balanced triangle. blockIdx.x in [0,45) -> chunk pair (a<=b);
// blockIdx.y in [0,16) -> 64-point j sub-tile of chunk b. Every block does
// 1024 x 64 pairs (uniform work). Symmetric form:
//   S = sum_{a<=b} wt * sum w_ij * g_ij,  g = s_i + s_j - 2 s_i s_j,
//   wt = 0.5 on diagonal chunk pairs (also yields the exact i==j term).
// Per thread: A = sum_j w, B = sum_j w*s_j; contribution s_i*A + (1-2 s_i)*B.
__global__ __launch_bounds__(256)
void crf_pair_kernel(const float4* __restrict__ arrF,
                     const float* __restrict__ arrS,
                     float* __restrict__ out) {
    __shared__ float4 shF[JSUB];
    __shared__ float wavesum[4];

    const int tid = threadIdx.x;

    // Decode triangular pair index -> (a, b), b >= a.
    int p = blockIdx.x, a = 0;
    while (p >= NCHUNK - a) { p -= NCHUNK - a; ++a; }
    const int b = a + p;
    const int ibase = a * CHUNK;
    const int jbase = b * CHUNK + blockIdx.y * JSUB;

    if (tid < JSUB) shF[tid] = arrF[jbase + tid];

    // My IPT=4 i-points; zero the s-lane so fdot2 sees (b_i, 0).
    half2v xyi[IPT], rgi[IPT], b0i[IPT];
    float  hsi[IPT], svi[IPT];
    #pragma unroll
    for (int k = 0; k < IPT; ++k) {
        int i = ibase + k * 256 + tid;
        float4 r = arrF[i];
        H2F u; u.f = r.x; xyi[k] = u.h;
        H2F v; v.f = r.y; rgi[k] = v.h;
        H2F w; w.f = r.z; w.h.y = (_Float16)0.0f; b0i[k] = w.h;
        hsi[k] = r.w;
        svi[k] = arrS[i];
    }

    __syncthreads();

    float A[IPT] = {0.f, 0.f, 0.f, 0.f};
    float B[IPT] = {0.f, 0.f, 0.f, 0.f};

    #pragma unroll 4
    for (int j = 0; j < JSUB; ++j) {
        float4 fj = shF[j];                  // one ds_read_b128, broadcast
        H2F u; u.f = fj.x;
        H2F v; v.f = fj.y;
        H2F w; w.f = fj.z;
        const half2v xyj = u.h, rgj = v.h, bsj = w.h;
        const float sjf = (float)w.h.y;      // j's s from the fp16 lane
        #pragma unroll
        for (int k = 0; k < IPT; ++k) {
            float e = hsi[k] + fj.w;
            e = __builtin_amdgcn_fdot2(xyi[k], xyj, e, false);
            e = __builtin_amdgcn_fdot2(rgi[k], rgj, e, false);
            e = __builtin_amdgcn_fdot2(b0i[k], bsj, e, false);  // s-lane x 0
            float wv = __builtin_amdgcn_exp2f(e);
            A[k] += wv;
            B[k] = fmaf(wv, sjf, B[k]);
        }
    }

    float t = 0.0f;
    #pragma unroll
    for (int k = 0; k < IPT; ++k)
        t += svi[k] * A[k] + fmaf(-2.0f * svi[k], B[k], B[k]);

    const float wt = (a == b) ? 0.5f : 1.0f;
    t *= wt * (1.0f / (float)NPTS);

    #pragma unroll
    for (int off = 32; off > 0; off >>= 1)
        t += __shfl_down(t, off, 64);
    if ((tid & 63) == 0) wavesum[tid >> 6] = t;
    __syncthreads();
    if (tid == 0)
        atomicAdd(out, wavesum[0] + wavesum[1] + wavesum[2] + wavesum[3]);
}

extern "C" void kernel_launch(void* const* d_in, const int* in_sizes, int n_in,
                              void* d_out, int out_size, void* d_ws, size_t ws_size,
                              hipStream_t stream) {
    const float* s   = (const float*)d_in[0];   // [1,1,96,96] probs
    const float* img = (const float*)d_in[1];   // [1,3,96,96] rgb
    float* out = (float*)d_out;

    float4* arrF = (float4*)d_ws;               // 9216 * 16 B
    float*  arrS = (float*)(arrF + NPTS);       // 9216 * 4 B

    crf_feat_kernel<<<NPTS/256, 256, 0, stream>>>(s, img, arrF, arrS, out);
    dim3 grid(NPAIR, NJSUB);
    crf_pair_kernel<<<grid, 256, 0, stream>>>(arrF, arrS, out);
}